// Round 14
// baseline (279.188 us; speedup 1.0000x reference)
//
#include <hip/hip_runtime.h>

#define NG 20000

// ---------- JAX threefry2x32, key = (0, 42) ----------
__device__ __forceinline__ void threefry2x32(unsigned x0, unsigned x1,
                                             unsigned& o0, unsigned& o1) {
  const unsigned ks0 = 0u;
  const unsigned ks1 = 42u;
  const unsigned ks2 = 0x1BD11BDAu ^ 0u ^ 42u;
  x0 += ks0; x1 += ks1;
#define TFR(r) { x0 += x1; x1 = (x1 << (r)) | (x1 >> (32 - (r))); x1 ^= x0; }
  TFR(13) TFR(15) TFR(26) TFR(6)
  x0 += ks1; x1 += ks2 + 1u;
  TFR(17) TFR(29) TFR(16) TFR(24)
  x0 += ks2; x1 += ks0 + 2u;
  TFR(13) TFR(15) TFR(26) TFR(6)
  x0 += ks0; x1 += ks1 + 3u;
  TFR(17) TFR(29) TFR(16) TFR(24)
  x0 += ks1; x1 += ks2 + 4u;
  TFR(13) TFR(15) TFR(26) TFR(6)
  x0 += ks2; x1 += ks0 + 5u;
#undef TFR
  o0 = x0; o1 = x1;
}

// JAX threefry_partitionable: bits(i) = o0 ^ o1 of threefry((0,42),(0,i))
__device__ __forceinline__ unsigned tfbits(unsigned ctr) {
  unsigned o0, o1;
  threefry2x32(0u, ctr, o0, o1);
  return o0 ^ o1;
}

// fp32 fast-screen gumbel, constant-folded: g = -ln2*log2(-log2(u)) - ln(ln2)
__device__ __forceinline__ float gumbel32(unsigned bits) {
  float f = __uint_as_float((bits >> 9) | 0x3f800000u) - 1.0f;
  float u = fmaxf(f, 1.17549435e-38f);
  const float l2u = __log2f(u);                     // strictly < 0
  return fmaf(-0.69314718056f, __log2f(-l2u), 0.3665129206f);
}

// exact fp64 gumbel; u is a 23-bit dyadic rational, exact in double
__device__ __forceinline__ double gumbel64(unsigned bits) {
  float f = __uint_as_float((bits >> 9) | 0x3f800000u) - 1.0f;
  double u = (double)fmaxf(f, 1.17549435e-38f);
  return -log(-log(u));
}

// pack fp64 score (top 49 monotone bits) + 15-bit (32767-n): u64 max == (score, then smaller n)
__device__ __forceinline__ unsigned long long packcell(double v, int n) {
  unsigned long long u = (unsigned long long)__double_as_longlong(v);
  u = (u >> 63) ? ~u : (u | 0x8000000000000000ull);
  return (u & 0xFFFFFFFFFFFF8000ull) | (unsigned long long)(32767 - n);
}

// ---------- prep: Wf=Wk@W1k (fp64 math, fp32 store), Q, qbT; c12; zero cells ----------
__global__ __launch_bounds__(128) void kprep(
    const float* __restrict__ pe, const float* __restrict__ Wq,
    const float* __restrict__ bq, const float* __restrict__ Wk,
    const float* __restrict__ bk, const float* __restrict__ W1,
    const float* __restrict__ b1, const float* __restrict__ w2,
    float* __restrict__ Wf32, double* __restrict__ qbT,
    float* __restrict__ Qm, unsigned long long* __restrict__ cells,
    double2* __restrict__ c12) {
  __shared__ float L[512];
  __shared__ double Ld[128];
  const int t = threadIdx.x;
  const int bid = blockIdx.x;
  if (bid < 256) {
    L[t] = Wk[bid * 128 + t];
    __syncthreads();
    double acc = 0.0;
    #pragma unroll 16
    for (int j = 0; j < 128; ++j)
      acc = fma((double)L[j], (double)W1[(128 + j) * 128 + t], acc);
    Wf32[bid * 128 + t] = (float)acc;
  } else if (bid < 320) {
    const int b = bid - 256;
    #pragma unroll
    for (int i = 0; i < 4; ++i) L[t + 128 * i] = pe[b * 512 + t + 128 * i];
    __syncthreads();
    double q = (double)bq[t];
    #pragma unroll 16
    for (int f = 0; f < 512; ++f)
      q = fma((double)L[f], (double)Wq[f * 128 + t], q);
    Qm[b * 128 + t] = (float)q;   // epilogue path stays fp32
    Ld[t] = q;
    __syncthreads();
    // qb[b,d=t] = Q@W1[:128] + b1 + bk@W1[128:]; store transposed qbT[d][b]
    double acc = (double)b1[t];
    #pragma unroll 8
    for (int j = 0; j < 128; ++j) {
      acc = fma(Ld[j], (double)W1[j * 128 + t], acc);
      acc = fma((double)bk[j], (double)W1[(128 + j) * 128 + t], acc);
    }
    qbT[t * 64 + b] = acc;
  } else {
    for (int i = t; i < 1280; i += 128) cells[i] = 0ull;
    const double w2d = (double)w2[t];
    c12[t] = make_double2(0.55 * w2d, 0.45 * w2d);
  }
}

// ---------- fully fused: kp(fp32 GEMM) + sim(fp64) + screen + exact + atomic ----------
// block = 256 threads, 16 genes (1250 blocks, 20000 = 1250*16 exact).
// Phase 1: wave wv owns genes wv*4..wv*4+3; thread owns d = lane, lane+64; ge tile
//   in LDS (broadcast ds_read_b128), Wf32 depth-2 register stream. fp32 fmaf,
//   per-acc f ascending -> kp bit-identical to R13.
// Phase 2: kp -> kpL; wave wv computes fp64 sim for genes {wv,wv+4,wv+8,wv+12},
//   lane = batch; stores (float)(2*sim) to simLf[b][g].
// Phase 3: thread handles 5 cells (cell = i*256+t); g-OUTER loop -> 5 independent
//   threefry chains per step (hides the 20-round dependent-chain latency).
//   Candidate order per cell ascending g, identical compares -> decisions
//   bit-identical to R13. One atomicMax per cell.
__global__ __launch_bounds__(256) void kfused(
    const float* __restrict__ ge, const float* __restrict__ Wf32,
    const double* __restrict__ qbT, const double2* __restrict__ c12,
    unsigned long long* __restrict__ cells) {
  __shared__ double SBd[2048];   // phase1: geL (16 KB as float); phase2/3: simLf
  __shared__ float kpL[2048];    // kp[16][128]
  float* geL = (float*)SBd;
  float* simLf = (float*)SBd;    // [64][17]
  const int t = threadIdx.x;
  const int wv = t >> 6;
  const int lane = t & 63;
  const int g0 = blockIdx.x * 16;     // 1250 blocks * 16 genes

  // stage ge tile (16 genes x 256 f) -> LDS: 4 independent float4 per thread
  {
    const float4* src = (const float4*)(ge + (size_t)g0 * 256);
    float4* dst = (float4*)geL;
    #pragma unroll
    for (int i = 0; i < 4; ++i) dst[t + i * 256] = src[t + i * 256];
  }
  __syncthreads();

  // ---- phase 1: fp32 GEMM from LDS genes + streamed Wf32 ----
  float acc[4][2];
  #pragma unroll
  for (int j = 0; j < 4; ++j) { acc[j][0] = 0.f; acc[j][1] = 0.f; }
  const float* wb0 = Wf32 + lane;
  const float* wb1 = Wf32 + lane + 64;
  const float* gL = geL + wv * 4 * 256;

  float wc0[4], wc1[4];
  #pragma unroll
  for (int ff = 0; ff < 4; ++ff) {
    wc0[ff] = wb0[ff * 128];
    wc1[ff] = wb1[ff * 128];
  }
  for (int f0 = 0; f0 < 256; f0 += 4) {
    float wn0[4], wn1[4];
    if (f0 < 252) {
      #pragma unroll
      for (int ff = 0; ff < 4; ++ff) {
        wn0[ff] = wb0[(f0 + 4 + ff) * 128];
        wn1[ff] = wb1[(f0 + 4 + ff) * 128];
      }
    }
    #pragma unroll
    for (int j = 0; j < 4; ++j) {
      const float4 gv = *(const float4*)(gL + j * 256 + f0);  // ds_read_b128 bcast
      acc[j][0] = fmaf(gv.x, wc0[0], acc[j][0]);
      acc[j][1] = fmaf(gv.x, wc1[0], acc[j][1]);
      acc[j][0] = fmaf(gv.y, wc0[1], acc[j][0]);
      acc[j][1] = fmaf(gv.y, wc1[1], acc[j][1]);
      acc[j][0] = fmaf(gv.z, wc0[2], acc[j][0]);
      acc[j][1] = fmaf(gv.z, wc1[2], acc[j][1]);
      acc[j][0] = fmaf(gv.w, wc0[3], acc[j][0]);
      acc[j][1] = fmaf(gv.w, wc1[3], acc[j][1]);
    }
    #pragma unroll
    for (int ff = 0; ff < 4; ++ff) { wc0[ff] = wn0[ff]; wc1[ff] = wn1[ff]; }
  }

  __syncthreads();   // geL reads done (SBd about to be reused as simLf)
  #pragma unroll
  for (int j = 0; j < 4; ++j) {
    kpL[(wv * 4 + j) * 128 + lane] = acc[j][0];
    kpL[(wv * 4 + j) * 128 + lane + 64] = acc[j][1];
  }
  __syncthreads();

  // ---- phase 2: fp64 sim (4 genes/wave, lane = batch) ----
  double s[4];
  #pragma unroll
  for (int j = 0; j < 4; ++j) s[j] = 0.0;
  for (int dd = 0; dd < 128; ++dd) {
    const double2 cc = c12[dd];                   // uniform -> s_load
    const double qv = qbT[dd * 64 + lane];        // coalesced, L1-hot
    #pragma unroll
    for (int j = 0; j < 4; ++j) {
      const double kv = (double)kpL[(wv + j * 4) * 128 + dd];  // broadcast
      const double tt = qv + kv;
      s[j] = fma(tt, cc.x, s[j]);
      s[j] = fma(fabs(tt), cc.y, s[j]);
    }
  }
  #pragma unroll
  for (int j = 0; j < 4; ++j)
    simLf[lane * 17 + (wv + j * 4)] = (float)(2.0 * s[j]);
  __syncthreads();

  // ---- phase 3: per-cell screen, g-outer for 5-way hash ILP ----
  float m1[5], m2[5];
  int n1[5], n2[5];
  unsigned c1[5], c2[5];
  int sbo[5];
  unsigned ib[5];
  #pragma unroll
  for (int i = 0; i < 5; ++i) {
    const int cell = i * 256 + t;                 // = b*20 + k, 0..1279
    sbo[i] = (int)((unsigned)cell / 20u) * 17;
    ib[i] = (unsigned)cell * 20000u + (unsigned)g0;
    m1[i] = -3e38f; m2[i] = -3e38f;
    n1[i] = -1; n2[i] = -1; c1[i] = 0u; c2[i] = 0u;
  }
  #pragma unroll 2
  for (int g = 0; g < 16; ++g) {
    #pragma unroll
    for (int i = 0; i < 5; ++i) {                 // 5 independent hash chains
      const unsigned bb = tfbits(ib[i] + (unsigned)g);
      const float sc = simLf[sbo[i] + g] + gumbel32(bb);
      if (sc > m1[i]) {
        m2[i] = m1[i]; n2[i] = n1[i]; c2[i] = c1[i];
        m1[i] = sc; n1[i] = g; c1[i] = bb;
      } else if (sc > m2[i]) {
        m2[i] = sc; n2[i] = g; c2[i] = bb;
      }
    }
  }
  #pragma unroll
  for (int i = 0; i < 5; ++i) {
    const int cell = i * 256 + t;
    unsigned long long pb =
        packcell((double)simLf[sbo[i] + n1[i]] + gumbel64(c1[i]), g0 + n1[i]);
    if (n2[i] >= 0 && (m1[i] - m2[i]) < 1e-4f) {  // screen err 2e-5 << margin
      const unsigned long long u2 =
          packcell((double)simLf[sbo[i] + n2[i]] + gumbel64(c2[i]), g0 + n2[i]);
      if (u2 > pb) pb = u2;
    }
    atomicMax(&cells[cell], pb);
  }
}

// ---------- epilogue (fp32): 5 interleaved V-GEMVs per wave, softmax over K, context ----------
__global__ __launch_bounds__(256) void kfinal(
    const float* __restrict__ ge, const float* __restrict__ Wv,
    const float* __restrict__ bv, const float* __restrict__ Qm,
    const unsigned long long* __restrict__ cells, float* __restrict__ out) {
  const int b = blockIdx.x;
  const int t = threadIdx.x;
  const int wv = t >> 6;
  const int lane = t & 63;
  __shared__ float sc[20];
  __shared__ float ctxp[4][128];
  const float2 qv = ((const float2*)(Qm + b * 128))[lane];
  const float2 bvv = ((const float2*)bv)[lane];
  const float* gr[5];
  float2 V[5];
  #pragma unroll
  for (int j = 0; j < 5; ++j) {
    const unsigned long long cell = cells[b * 20 + wv * 5 + j];
    const int n = 32767 - (int)(cell & 0x7FFFull);
    gr[j] = ge + (size_t)n * 256;
    V[j] = bvv;
  }
  for (int f = 0; f < 256; f += 4) {
    const float2 w0 = ((const float2*)(Wv + (size_t)(f + 0) * 128))[lane];
    const float2 w1 = ((const float2*)(Wv + (size_t)(f + 1) * 128))[lane];
    const float2 w2_ = ((const float2*)(Wv + (size_t)(f + 2) * 128))[lane];
    const float2 w3 = ((const float2*)(Wv + (size_t)(f + 3) * 128))[lane];
    #pragma unroll
    for (int j = 0; j < 5; ++j) {
      const float4 gv = *(const float4*)(gr[j] + f);   // uniform -> s_load
      V[j].x = fmaf(gv.x, w0.x, V[j].x); V[j].y = fmaf(gv.x, w0.y, V[j].y);
      V[j].x = fmaf(gv.y, w1.x, V[j].x); V[j].y = fmaf(gv.y, w1.y, V[j].y);
      V[j].x = fmaf(gv.z, w2_.x, V[j].x); V[j].y = fmaf(gv.z, w2_.y, V[j].y);
      V[j].x = fmaf(gv.w, w3.x, V[j].x); V[j].y = fmaf(gv.w, w3.y, V[j].y);
    }
  }
  #pragma unroll
  for (int j = 0; j < 5; ++j) {
    float pr = qv.x * V[j].x + qv.y * V[j].y;
    #pragma unroll
    for (int off = 32; off; off >>= 1) pr += __shfl_xor(pr, off, 64);
    if (lane == 0) sc[wv * 5 + j] = pr * 0.08838834764831845f;  // 1/sqrt(128)
  }
  __syncthreads();
  float m = -3.0e38f;
  #pragma unroll
  for (int i = 0; i < 20; ++i) m = fmaxf(m, sc[i]);
  float s = 0.f;
  #pragma unroll
  for (int i = 0; i < 20; ++i) s += expf(sc[i] - m);
  const float inv = 1.0f / s;
  float c0 = 0.f, c1 = 0.f;
  #pragma unroll
  for (int j = 0; j < 5; ++j) {
    const float wk = expf(sc[wv * 5 + j] - m) * inv;
    c0 = fmaf(wk, V[j].x, c0);
    c1 = fmaf(wk, V[j].y, c1);
  }
  ctxp[wv][2 * lane] = c0;
  ctxp[wv][2 * lane + 1] = c1;
  __syncthreads();
  if (t < 128)
    out[b * 128 + t] = (ctxp[0][t] + ctxp[1][t]) + (ctxp[2][t] + ctxp[3][t]);
}

extern "C" void kernel_launch(void* const* d_in, const int* in_sizes, int n_in,
                              void* d_out, int out_size, void* d_ws, size_t ws_size,
                              hipStream_t stream) {
  (void)in_sizes; (void)n_in; (void)out_size; (void)ws_size;
  const float* pe = (const float*)d_in[0];
  const float* ge = (const float*)d_in[1];
  const float* Wq = (const float*)d_in[2];
  const float* bq = (const float*)d_in[3];
  const float* Wk = (const float*)d_in[4];
  const float* bk = (const float*)d_in[5];
  const float* Wv = (const float*)d_in[6];
  const float* bvp = (const float*)d_in[7];
  const float* W1 = (const float*)d_in[8];
  const float* b1 = (const float*)d_in[9];
  const float* w2 = (const float*)d_in[10];
  // d_in[11] = b2: uniform over n -> cancels in argmax; absent from output path.

  char* w = (char*)d_ws;
  float* Wf32 = (float*)w;                               // 131072 B
  double* qbT = (double*)(w + 131072);                   // 65536 B
  float* Qm = (float*)(w + 196608);                      // 32768 B
  unsigned long long* cells =
      (unsigned long long*)(w + 229376);                 // 10240 B
  double2* c12 = (double2*)(w + 239616);                 // 2048 B (~0.24 MB total)
  float* out = (float*)d_out;

  kprep<<<dim3(321), dim3(128), 0, stream>>>(pe, Wq, bq, Wk, bk, W1, b1, w2,
                                             Wf32, qbT, Qm, cells, c12);
  kfused<<<dim3(1250), dim3(256), 0, stream>>>(ge, Wf32, qbT, c12, cells);
  kfinal<<<dim3(64), dim3(256), 0, stream>>>(ge, Wv, bvp, Qm, cells, out);
}